// Round 14
// baseline (157.140 us; speedup 1.0000x reference)
//
#include <hip/hip_runtime.h>
#include <hip/hip_cooperative_groups.h>

namespace cg = cooperative_groups;

#define NB 2
#define NN 2048
#define NC 16
#define NFG 15
#define NPAIR (NB * NFG)
#define DETS 100
#define TH1 512
#define TKEEP 256
#define SCORE_TH 0.05f
#define NMS_TH 0.5f
#define BBOX_CLIP 4.135166556742356f
#define IMG_MAX 1023.0f

typedef unsigned long long ull;

__device__ __forceinline__ float iou_box(float4 a, float aarea, float4 c) {
    float xx1 = fmaxf(a.x, c.x);
    float yy1 = fmaxf(a.y, c.y);
    float xx2 = fminf(a.z, c.z);
    float yy2 = fminf(a.w, c.w);
    float iw = fmaxf(__fadd_rn(__fsub_rn(xx2, xx1), 1.0f), 0.0f);
    float ih = fmaxf(__fadd_rn(__fsub_rn(yy2, yy1), 1.0f), 0.0f);
    float inter = __fmul_rn(iw, ih);
    float carea = __fmul_rn(__fadd_rn(__fsub_rn(c.z, c.x), 1.0f),
                            __fadd_rn(__fsub_rn(c.w, c.y), 1.0f));
    float denom = __fsub_rn(__fadd_rn(aarea, carea), inter);
    return __fdiv_rn(inter, denom);
}

// Hybrid bitonic sort of 2048 u64 keys, descending. blockDim must be 512.
__device__ __forceinline__ void bitonic2048(ull* keys, int tid) {
    ull r[4];
#pragma unroll
    for (int p = 0; p < 4; ++p) r[p] = keys[tid + p * TH1];

#pragma unroll
    for (unsigned k = 2; k <= 64; k <<= 1) {
        for (unsigned j = k >> 1; j >= 1; j >>= 1) {
#pragma unroll
            for (int p = 0; p < 4; ++p) {
                ull v = __shfl_xor(r[p], (int)j);
                unsigned i = (unsigned)tid + (unsigned)p * TH1;
                bool keepMax = ((((unsigned)tid & j) == 0u) == ((i & k) == 0u));
                bool agtv = r[p] > v;
                r[p] = (agtv == keepMax) ? r[p] : v;
            }
        }
    }
#pragma unroll
    for (int p = 0; p < 4; ++p) keys[tid + p * TH1] = r[p];

    for (unsigned k = 128; k <= 2048; k <<= 1) {
        for (unsigned j = k >> 1; j >= 64; j >>= 1) {
            __syncthreads();
            for (unsigned i = tid; i < NN; i += TH1) {
                unsigned ixj = i ^ j;
                if (ixj > i) {
                    ull a = keys[i], c = keys[ixj];
                    bool sw = ((i & k) == 0) ? (a < c) : (a > c);
                    if (sw) { keys[i] = c; keys[ixj] = a; }
                }
            }
        }
        __syncthreads();
#pragma unroll
        for (int p = 0; p < 4; ++p) r[p] = keys[tid + p * TH1];
        for (unsigned j = 32; j >= 1; j >>= 1) {
#pragma unroll
            for (int p = 0; p < 4; ++p) {
                ull v = __shfl_xor(r[p], (int)j);
                unsigned i = (unsigned)tid + (unsigned)p * TH1;
                bool keepMax = ((((unsigned)tid & j) == 0u) == ((i & k) == 0u));
                bool agtv = r[p] > v;
                r[p] = (agtv == keepMax) ? r[p] : v;
            }
        }
#pragma unroll
        for (int p = 0; p < 4; ++p) keys[tid + p * TH1] = r[p];
    }
    __syncthreads();
}

// -------- Fused cooperative kernel: score -> per-pair NMS -> per-image top-k --------
__global__ __launch_bounds__(TH1)
void fused_kernel(const float* __restrict__ logits,
                  const float* __restrict__ deltas,
                  const float* __restrict__ props,
                  float* __restrict__ out,
                  float* __restrict__ scoreAll,  // [NPAIR][NN]
                  ull*   __restrict__ cKey,      // [NPAIR][DETS]
                  float* __restrict__ cBox,      // [NPAIR][DETS][4]
                  float* __restrict__ cTheta)    // [NPAIR][DETS]
{
    cg::grid_group grid = cg::this_grid();
    const int bid  = blockIdx.x;
    const int tid  = threadIdx.x;
    const int lane = tid & 63;

    __shared__ ull keys[NN];                  // 16 KB
    __shared__ float4 sbl[NN];                // 32 KB
    __shared__ ull supmat[4][TKEEP];          //  8 KB (w-major: conflict-free writes)
    __shared__ ull remW[NN/64];               // 256 B
    __shared__ int keptPos[DETS];             // 400 B
    __shared__ int keptCnt;

    // ================= Phase S: softmax scores for all (b, n) =================
    {
        const int g = bid * TH1 + tid;        // blocks 0..7 cover 4096 items
        if (g < NB * NN) {
            const int b = g >> 11;
            const int n = g & (NN - 1);
            const float* lr = logits + (size_t)(b * NN + n) * NC;
            float l[NC];
#pragma unroll
            for (int t = 0; t < NC / 4; ++t) {
                float4 v = ((const float4*)lr)[t];
                l[4*t+0] = v.x; l[4*t+1] = v.y; l[4*t+2] = v.z; l[4*t+3] = v.w;
            }
            float m = l[0];
#pragma unroll
            for (int c = 1; c < NC; ++c) m = fmaxf(m, l[c]);
            float e[NC];
            float sum = 0.0f;
#pragma unroll
            for (int c = 0; c < NC; ++c) {
                e[c] = expf(__fsub_rn(l[c], m));
                sum = __fadd_rn(sum, e[c]);
            }
#pragma unroll
            for (int cf = 0; cf < NFG; ++cf) {
                scoreAll[(size_t)(b * NFG + cf) * NN + n] = __fdiv_rn(e[cf + 1], sum);
            }
        }
    }
    grid.sync();

    // ================= Phase N: per (image,class) sort + NMS =================
    if (bid < NPAIR) {
        const int pair = bid;
        const int b    = pair / NFG;
        const int cls  = pair % NFG + 1;

        const float* D = deltas + (size_t)b * NN * NC * 5;
        const float* P = props  + (size_t)b * NN * 4;
        const float* S = scoreAll + (size_t)pair * NN;

        // ---- coalesced score read -> stable-descending keys ----
        for (int n = tid; n < NN; n += TH1) {
            float sc = S[n];
            keys[n] = ((ull)__float_as_uint(sc) << 32) | (unsigned)(NN - 1 - n);
        }
        __syncthreads();

        bitonic2048(keys, tid);

        // ---- valid bitmask (valid = prefix of sorted order) ----
        for (int n = tid; n < NN; n += TH1) {
            float sc = __uint_as_float((unsigned)(keys[n] >> 32));
            ull bm = __ballot(sc > SCORE_TH);
            if (lane == 0) remW[n >> 6] = bm;
        }

        // ---- decode boxes only for top TKEEP sorted slots ----
        for (int n = tid; n < TKEEP; n += TH1) {
            ull key = keys[n];
            int orig = NN - 1 - (int)(key & 0xFFFFFFFFull);

            float4 pv = ((const float4*)P)[orig];
            float w  = __fadd_rn(__fsub_rn(pv.z, pv.x), 1.0f);
            float h  = __fadd_rn(__fsub_rn(pv.w, pv.y), 1.0f);
            float cx = __fadd_rn(pv.x, __fmul_rn(0.5f, w));
            float cy = __fadd_rn(pv.y, __fmul_rn(0.5f, h));

            const float* dd = D + (size_t)orig * NC * 5 + cls * 5;
            float dx = __fdiv_rn(dd[0], 10.0f);
            float dy = __fdiv_rn(dd[1], 10.0f);
            float dw = fminf(__fdiv_rn(dd[2], 5.0f), BBOX_CLIP);
            float dh = fminf(__fdiv_rn(dd[3], 5.0f), BBOX_CLIP);

            float pcx = __fadd_rn(__fmul_rn(dx, w), cx);
            float pcy = __fadd_rn(__fmul_rn(dy, h), cy);
            float pw  = __fmul_rn(expf(dw), w);
            float ph  = __fmul_rn(expf(dh), h);

            float bx1 = __fsub_rn(pcx, __fmul_rn(0.5f, pw));
            float by1 = __fsub_rn(pcy, __fmul_rn(0.5f, ph));
            float bx2 = __fsub_rn(__fadd_rn(pcx, __fmul_rn(0.5f, pw)), 1.0f);
            float by2 = __fsub_rn(__fadd_rn(pcy, __fmul_rn(0.5f, ph)), 1.0f);

            bx1 = fminf(fmaxf(bx1, 0.0f), IMG_MAX);
            by1 = fminf(fmaxf(by1, 0.0f), IMG_MAX);
            bx2 = fminf(fmaxf(bx2, 0.0f), IMG_MAX);
            by2 = fminf(fmaxf(by2, 0.0f), IMG_MAX);

            sbl[n] = make_float4(bx1, by1, bx2, by2);
        }
        __syncthreads();

        // ---- C1: suppression matrix; i lane-consecutive, w wave-uniform ----
        for (int p = 0; p < (TKEEP * 4) / TH1; ++p) {
            int item = p * TH1 + tid;             // 0..1023
            int i = item & (TKEEP - 1);           // row (coalesced 'a' read)
            int w = item >> 8;                    // 64-col word (uniform -> broadcast)
            float4 a = sbl[i];
            float aarea = __fmul_rn(__fadd_rn(__fsub_rn(a.z, a.x), 1.0f),
                                    __fadd_rn(__fsub_rn(a.w, a.y), 1.0f));
            ull m = 0ull;
#pragma unroll 8
            for (int l = 0; l < 64; ++l) {
                float iou = iou_box(a, aarea, sbl[(w << 6) + l]);
                if (iou > NMS_TH) m |= (1ull << l);
            }
            supmat[w][i] = m;
        }
        __syncthreads();

        // ---- C2: single-wave barrier-free greedy resolve over first TKEEP ----
        if (tid < 64) {
            ull rem = (lane < TKEEP / 64) ? remW[lane] : 0ull;
            int kept = 0;
            while (kept < DETS) {
                ull has = __ballot(rem != 0ull);
                if (has == 0ull) break;
                int fw = (int)__builtin_ctzll(has);
                unsigned lo = (unsigned)__shfl((int)(unsigned)rem, fw);
                unsigned hi = (unsigned)__shfl((int)(unsigned)(rem >> 32), fw);
                ull w64 = ((ull)hi << 32) | lo;
                int i = (fw << 6) + (int)__builtin_ctzll(w64);
                if (lane == 0) keptPos[kept] = i;
                ++kept;
                if (lane < TKEEP / 64) rem &= ~supmat[lane][i];  // self-bit cleared (IoU=1)
            }
            if (lane == 0) keptCnt = kept;
        }
        __syncthreads();

        // ---- C3: exact fallback if TKEEP insufficient (never triggers on this data) ----
        int keptNow = keptCnt;
        if (keptNow < DETS) {
            for (int n = TKEEP + tid; n < NN; n += TH1) {
                ull key = keys[n];
                int orig = NN - 1 - (int)(key & 0xFFFFFFFFull);
                float4 pv = ((const float4*)P)[orig];
                float w  = __fadd_rn(__fsub_rn(pv.z, pv.x), 1.0f);
                float h  = __fadd_rn(__fsub_rn(pv.w, pv.y), 1.0f);
                float cx = __fadd_rn(pv.x, __fmul_rn(0.5f, w));
                float cy = __fadd_rn(pv.y, __fmul_rn(0.5f, h));
                const float* dd = D + (size_t)orig * NC * 5 + cls * 5;
                float dx = __fdiv_rn(dd[0], 10.0f);
                float dy = __fdiv_rn(dd[1], 10.0f);
                float dw = fminf(__fdiv_rn(dd[2], 5.0f), BBOX_CLIP);
                float dh = fminf(__fdiv_rn(dd[3], 5.0f), BBOX_CLIP);
                float pcx = __fadd_rn(__fmul_rn(dx, w), cx);
                float pcy = __fadd_rn(__fmul_rn(dy, h), cy);
                float pw  = __fmul_rn(expf(dw), w);
                float ph  = __fmul_rn(expf(dh), h);
                float bx1 = __fsub_rn(pcx, __fmul_rn(0.5f, pw));
                float by1 = __fsub_rn(pcy, __fmul_rn(0.5f, ph));
                float bx2 = __fsub_rn(__fadd_rn(pcx, __fmul_rn(0.5f, pw)), 1.0f);
                float by2 = __fsub_rn(__fadd_rn(pcy, __fmul_rn(0.5f, ph)), 1.0f);
                bx1 = fminf(fmaxf(bx1, 0.0f), IMG_MAX);
                by1 = fminf(fmaxf(by1, 0.0f), IMG_MAX);
                bx2 = fminf(fmaxf(bx2, 0.0f), IMG_MAX);
                by2 = fminf(fmaxf(by2, 0.0f), IMG_MAX);
                sbl[n] = make_float4(bx1, by1, bx2, by2);
            }
            if (tid < TKEEP / 64) remW[tid] = 0ull;
            __syncthreads();
            for (int k = 0; k < NN / TH1; ++k) {
                int j = k * TH1 + tid;
                bool sup = false;
                if (j >= TKEEP) {
                    float4 c = sbl[j];
                    for (int q = 0; q < keptNow; ++q) {
                        float4 a = sbl[keptPos[q]];
                        float aarea = __fmul_rn(__fadd_rn(__fsub_rn(a.z, a.x), 1.0f),
                                                __fadd_rn(__fsub_rn(a.w, a.y), 1.0f));
                        sup = sup || (iou_box(a, aarea, c) > NMS_TH);
                    }
                }
                ull bm = __ballot(sup);
                if (lane == 0) remW[k * (TH1/64) + (tid >> 6)] &= ~bm;
            }
            __syncthreads();
            int kept = keptNow;
            while (kept < DETS) {
                ull mine = (lane < NN / 64) ? remW[lane] : 0ull;
                ull has = __ballot(mine != 0ull);
                if (has == 0ull) break;
                int fw = (int)__builtin_ctzll(has);
                unsigned lo = (unsigned)__shfl((int)(unsigned)mine, fw);
                unsigned hi = (unsigned)__shfl((int)(unsigned)(mine >> 32), fw);
                ull w64 = ((ull)hi << 32) | lo;
                int i = (fw << 6) + (int)__builtin_ctzll(w64);
                if (tid == 0) keptPos[kept] = i;
                ++kept;
                __syncthreads();
                float4 a = sbl[i];
                float aarea = __fmul_rn(__fadd_rn(__fsub_rn(a.z, a.x), 1.0f),
                                        __fadd_rn(__fsub_rn(a.w, a.y), 1.0f));
#pragma unroll
                for (int k = 0; k < NN / TH1; ++k) {
                    int j = k * TH1 + tid;
                    float iou = iou_box(a, aarea, sbl[j]);
                    ull bm = __ballot(iou > NMS_TH);
                    if (lane == 0) remW[k * (TH1/64) + (tid >> 6)] &= ~bm;
                }
                __syncthreads();
            }
            if (tid == 0) keptCnt = kept;
            __syncthreads();
        }

        // ---- compact first <=100 kept + packed keys for the final top-k sort ----
        if (tid < DETS) {
            int kc = keptCnt;
            float sc = -1.0f, th = 0.0f;
            float4 bx = make_float4(0.f, 0.f, 0.f, 0.f);
            if (tid < kc) {
                int p = keptPos[tid];
                ull key = keys[p];
                sc = __uint_as_float((unsigned)(key >> 32));
                bx = sbl[p];
                int orig = NN - 1 - (int)(key & 0xFFFFFFFFull);
                th = D[(size_t)orig * NC * 5 + cls * 5 + 4];
            }
            int g = pair * DETS + tid;
            unsigned vb = __float_as_uint(sc);
            vb = (vb & 0x80000000u) ? ~vb : (vb | 0x80000000u);   // orderable
            cKey[g] = ((ull)vb << 32)
                    | (unsigned)(NN - 1 - ((pair % NFG) * DETS + tid));
            cTheta[g] = th;
            ((float4*)cBox)[g] = bx;
        }
    }
    grid.sync();

    // ================= Phase T: per-image top-100 (blocks 0..1) =================
    if (bid < NB) {
        const int b = bid;
        const int M = NFG * DETS;   // 1500

        const ull* src = cKey + (size_t)b * M;
        for (int t = tid; t < NN; t += TH1)
            keys[t] = (t < M) ? src[t] : 0ull;   // pad sorts last
        __syncthreads();

        bitonic2048(keys, tid);

        if (tid < DETS) {
            ull key = keys[tid];
            unsigned vb = (unsigned)(key >> 32);
            float val = __uint_as_float((vb & 0x80000000u) ? (vb & 0x7FFFFFFFu) : ~vb);
            bool vld = (key != 0ull) && (val > 0.0f);
            float4 bx = make_float4(0.f, 0.f, 0.f, 0.f);
            float th = 0.f, lab = 0.f, scv = 0.f;
            if (vld) {
                int slot = NN - 1 - (int)(key & 0xFFFFFFFFull);  // clsfg*DETS + cidx
                size_t g = (size_t)b * M + slot;
                bx  = ((const float4*)cBox)[g];
                th  = cTheta[g];
                lab = (float)(slot / DETS + 1);
                scv = val;
            }
            int o = b * DETS + tid;
            out[o * 4 + 0] = bx.x;
            out[o * 4 + 1] = bx.y;
            out[o * 4 + 2] = bx.z;
            out[o * 4 + 3] = bx.w;
            out[NB * DETS * 4 + o] = scv;
            out[NB * DETS * 5 + o] = th;
            out[NB * DETS * 6 + o] = lab;
            out[NB * DETS * 7 + o] = vld ? 1.0f : 0.0f;
        }
    }
}

extern "C" void kernel_launch(void* const* d_in, const int* in_sizes, int n_in,
                              void* d_out, int out_size, void* d_ws, size_t ws_size,
                              hipStream_t stream) {
    const float* logits = (const float*)d_in[0];   // [2,2048,16]
    const float* deltas = (const float*)d_in[1];   // [2,2048,80]
    const float* props  = (const float*)d_in[2];   // [2,2048,4]
    float* out = (float*)d_out;                    // 1600 floats
    char* ws = (char*)d_ws;

    ull*   cKey     = (ull*)ws;                                   // NPAIR*DETS u64
    float* cBox     = (float*)(ws + sizeof(ull) * NPAIR * DETS);  // NPAIR*DETS*4
    float* cTheta   = cBox + (size_t)NPAIR * DETS * 4;            // NPAIR*DETS
    float* scoreAll = cTheta + (size_t)NPAIR * DETS;              // NPAIR*NN

    void* args[] = { (void*)&logits, (void*)&deltas, (void*)&props, (void*)&out,
                     (void*)&scoreAll, (void*)&cKey, (void*)&cBox, (void*)&cTheta };
    hipLaunchCooperativeKernel((const void*)fused_kernel, dim3(NPAIR), dim3(TH1),
                               args, 0, stream);
}

// Round 15
// 118.454 us; speedup vs baseline: 1.3266x; 1.3266x over previous
//
#include <hip/hip_runtime.h>

#define NB 2
#define NN 2048
#define NC 16
#define NFG 15
#define NPAIR (NB * NFG)
#define DETS 100
#define TH1 512
#define TKEEP 128
#define SCORE_TH 0.05f
#define NMS_TH 0.5f
#define BBOX_CLIP 4.135166556742356f
#define IMG_MAX 1023.0f

typedef unsigned long long ull;

__device__ __forceinline__ float iou_box(float4 a, float aarea, float4 c) {
    float xx1 = fmaxf(a.x, c.x);
    float yy1 = fmaxf(a.y, c.y);
    float xx2 = fminf(a.z, c.z);
    float yy2 = fminf(a.w, c.w);
    float iw = fmaxf(__fadd_rn(__fsub_rn(xx2, xx1), 1.0f), 0.0f);
    float ih = fmaxf(__fadd_rn(__fsub_rn(yy2, yy1), 1.0f), 0.0f);
    float inter = __fmul_rn(iw, ih);
    float carea = __fmul_rn(__fadd_rn(__fsub_rn(c.z, c.x), 1.0f),
                            __fadd_rn(__fsub_rn(c.w, c.y), 1.0f));
    float denom = __fsub_rn(__fadd_rn(aarea, carea), inter);
    return __fdiv_rn(inter, denom);
}

// Hybrid bitonic sort of 2048 u64 keys, descending. blockDim must be 512.
// j<64 phases run in registers via shfl (no barrier); only j>=64 touch LDS.
__device__ __forceinline__ void bitonic2048(ull* keys, int tid) {
    ull r[4];
#pragma unroll
    for (int p = 0; p < 4; ++p) r[p] = keys[tid + p * TH1];

#pragma unroll
    for (unsigned k = 2; k <= 64; k <<= 1) {
        for (unsigned j = k >> 1; j >= 1; j >>= 1) {
#pragma unroll
            for (int p = 0; p < 4; ++p) {
                ull v = __shfl_xor(r[p], (int)j);
                unsigned i = (unsigned)tid + (unsigned)p * TH1;
                bool keepMax = ((((unsigned)tid & j) == 0u) == ((i & k) == 0u));
                bool agtv = r[p] > v;
                r[p] = (agtv == keepMax) ? r[p] : v;
            }
        }
    }
#pragma unroll
    for (int p = 0; p < 4; ++p) keys[tid + p * TH1] = r[p];

    for (unsigned k = 128; k <= 2048; k <<= 1) {
        for (unsigned j = k >> 1; j >= 64; j >>= 1) {
            __syncthreads();
            for (unsigned i = tid; i < NN; i += TH1) {
                unsigned ixj = i ^ j;
                if (ixj > i) {
                    ull a = keys[i], c = keys[ixj];
                    bool sw = ((i & k) == 0) ? (a < c) : (a > c);
                    if (sw) { keys[i] = c; keys[ixj] = a; }
                }
            }
        }
        __syncthreads();
#pragma unroll
        for (int p = 0; p < 4; ++p) r[p] = keys[tid + p * TH1];
        for (unsigned j = 32; j >= 1; j >>= 1) {
#pragma unroll
            for (int p = 0; p < 4; ++p) {
                ull v = __shfl_xor(r[p], (int)j);
                unsigned i = (unsigned)tid + (unsigned)p * TH1;
                bool keepMax = ((((unsigned)tid & j) == 0u) == ((i & k) == 0u));
                bool agtv = r[p] > v;
                r[p] = (agtv == keepMax) ? r[p] : v;
            }
        }
#pragma unroll
        for (int p = 0; p < 4; ++p) keys[tid + p * TH1] = r[p];
    }
    __syncthreads();
}

// -------- Kernel 0: parallel softmax for all (b, n) --------
__global__ __launch_bounds__(256)
void score_kernel(const float* __restrict__ logits,
                  float* __restrict__ scoreAll)   // [NPAIR][NN]
{
    const int g = blockIdx.x * 256 + threadIdx.x;   // 0..4095
    const int b = g >> 11;
    const int n = g & (NN - 1);

    const float* lr = logits + (size_t)(b * NN + n) * NC;
    float l[NC];
#pragma unroll
    for (int t = 0; t < NC / 4; ++t) {
        float4 v = ((const float4*)lr)[t];
        l[4*t+0] = v.x; l[4*t+1] = v.y; l[4*t+2] = v.z; l[4*t+3] = v.w;
    }
    float m = l[0];
#pragma unroll
    for (int c = 1; c < NC; ++c) m = fmaxf(m, l[c]);
    float e[NC];
    float sum = 0.0f;
#pragma unroll
    for (int c = 0; c < NC; ++c) {
        e[c] = expf(__fsub_rn(l[c], m));
        sum = __fadd_rn(sum, e[c]);
    }
#pragma unroll
    for (int cf = 0; cf < NFG; ++cf) {
        scoreAll[(size_t)(b * NFG + cf) * NN + n] = __fdiv_rn(e[cf + 1], sum);
    }
}

// -------- Kernel 1: per (image,class) sort + deferred decode + matrix-NMS + compaction ----
__global__ __launch_bounds__(TH1)
void nms_kernel(const float* __restrict__ scoreAll,
                const float* __restrict__ deltas,
                const float* __restrict__ props,
                ull*   __restrict__ cKey,    // [NPAIR][DETS] packed orderable keys
                float* __restrict__ cBox,    // [NPAIR][DETS][4]
                float* __restrict__ cTheta)  // [NPAIR][DETS]
{
    const int pair = blockIdx.x;       // 0..29
    const int b    = pair / NFG;
    const int cls  = pair % NFG + 1;   // foreground class 1..15
    const int tid  = threadIdx.x;
    const int lane = tid & 63;

    const float* D = deltas + (size_t)b * NN * NC * 5;
    const float* P = props  + (size_t)b * NN * 4;
    const float* S = scoreAll + (size_t)pair * NN;

    __shared__ ull keys[NN];                  // 16 KB (intact after sort)
    __shared__ float4 sbl[NN];                // 32 KB sorted boxes (top-TKEEP in fast path)
    __shared__ ull supmat[TKEEP/64][TKEEP];   //  2 KB (w-major: conflict-free)
    __shared__ ull remW[NN/64];               // 256 B remaining-candidate bitmask
    __shared__ int keptPos[DETS];             // 400 B
    __shared__ int keptCnt;

    // ---- Phase A: coalesced score read -> stable-descending keys ----
    for (int n = tid; n < NN; n += TH1) {
        float sc = S[n];
        keys[n] = ((ull)__float_as_uint(sc) << 32) | (unsigned)(NN - 1 - n);
    }
    __syncthreads();

    bitonic2048(keys, tid);

    // ---- valid bitmask from keys (valid = prefix of sorted order) ----
    for (int n = tid; n < NN; n += TH1) {
        float sc = __uint_as_float((unsigned)(keys[n] >> 32));
        ull bm = __ballot(sc > SCORE_TH);
        if (lane == 0) remW[n >> 6] = bm;   // n strided by 512: word-aligned per wave
    }

    // ---- Phase B: decode boxes only for top TKEEP sorted slots ----
    for (int n = tid; n < TKEEP; n += TH1) {
        ull key = keys[n];
        int orig = NN - 1 - (int)(key & 0xFFFFFFFFull);

        float4 pv = ((const float4*)P)[orig];
        float w  = __fadd_rn(__fsub_rn(pv.z, pv.x), 1.0f);
        float h  = __fadd_rn(__fsub_rn(pv.w, pv.y), 1.0f);
        float cx = __fadd_rn(pv.x, __fmul_rn(0.5f, w));
        float cy = __fadd_rn(pv.y, __fmul_rn(0.5f, h));

        const float* dd = D + (size_t)orig * NC * 5 + cls * 5;
        float dx = __fdiv_rn(dd[0], 10.0f);
        float dy = __fdiv_rn(dd[1], 10.0f);
        float dw = fminf(__fdiv_rn(dd[2], 5.0f), BBOX_CLIP);
        float dh = fminf(__fdiv_rn(dd[3], 5.0f), BBOX_CLIP);

        float pcx = __fadd_rn(__fmul_rn(dx, w), cx);
        float pcy = __fadd_rn(__fmul_rn(dy, h), cy);
        float pw  = __fmul_rn(expf(dw), w);
        float ph  = __fmul_rn(expf(dh), h);

        float bx1 = __fsub_rn(pcx, __fmul_rn(0.5f, pw));
        float by1 = __fsub_rn(pcy, __fmul_rn(0.5f, ph));
        float bx2 = __fsub_rn(__fadd_rn(pcx, __fmul_rn(0.5f, pw)), 1.0f);
        float by2 = __fsub_rn(__fadd_rn(pcy, __fmul_rn(0.5f, ph)), 1.0f);

        bx1 = fminf(fmaxf(bx1, 0.0f), IMG_MAX);
        by1 = fminf(fmaxf(by1, 0.0f), IMG_MAX);
        bx2 = fminf(fmaxf(bx2, 0.0f), IMG_MAX);
        by2 = fminf(fmaxf(by2, 0.0f), IMG_MAX);

        sbl[n] = make_float4(bx1, by1, bx2, by2);
    }
    __syncthreads();

    // ---- C1: suppression matrix; i lane-consecutive, w wave-uniform (conflict-free) ----
    for (int t = tid; t < TKEEP * (TKEEP / 64); t += TH1) {
        int i = t & (TKEEP - 1);              // row (coalesced 'a' read)
        int w = t >> 7;                       // 64-col word (wave-uniform -> broadcast)
        float4 a = sbl[i];
        float aarea = __fmul_rn(__fadd_rn(__fsub_rn(a.z, a.x), 1.0f),
                                __fadd_rn(__fsub_rn(a.w, a.y), 1.0f));
        ull m = 0ull;
#pragma unroll 8
        for (int l = 0; l < 64; ++l) {
            float iou = iou_box(a, aarea, sbl[(w << 6) + l]);
            if (iou > NMS_TH) m |= (1ull << l);
        }
        supmat[w][i] = m;
    }
    __syncthreads();

    // ---- C2: single-wave barrier-free greedy resolve over first TKEEP ----
    if (tid < 64) {
        ull rem = (lane < TKEEP / 64) ? remW[lane] : 0ull;
        int kept = 0;
        while (kept < DETS) {
            ull has = __ballot(rem != 0ull);
            if (has == 0ull) break;
            int fw = (int)__builtin_ctzll(has);
            unsigned lo = (unsigned)__shfl((int)(unsigned)rem, fw);
            unsigned hi = (unsigned)__shfl((int)(unsigned)(rem >> 32), fw);
            ull w64 = ((ull)hi << 32) | lo;
            int i = (fw << 6) + (int)__builtin_ctzll(w64);
            if (lane == 0) keptPos[kept] = i;
            ++kept;
            if (lane < TKEEP / 64) rem &= ~supmat[lane][i];   // self-bit cleared (IoU=1)
        }
        if (lane == 0) keptCnt = kept;
    }
    __syncthreads();

    // ---- C3: exact fallback if TKEEP insufficient (never triggers on this data) ----
    int keptNow = keptCnt;
    if (keptNow < DETS) {
        for (int n = TKEEP + tid; n < NN; n += TH1) {
            ull key = keys[n];
            int orig = NN - 1 - (int)(key & 0xFFFFFFFFull);
            float4 pv = ((const float4*)P)[orig];
            float w  = __fadd_rn(__fsub_rn(pv.z, pv.x), 1.0f);
            float h  = __fadd_rn(__fsub_rn(pv.w, pv.y), 1.0f);
            float cx = __fadd_rn(pv.x, __fmul_rn(0.5f, w));
            float cy = __fadd_rn(pv.y, __fmul_rn(0.5f, h));
            const float* dd = D + (size_t)orig * NC * 5 + cls * 5;
            float dx = __fdiv_rn(dd[0], 10.0f);
            float dy = __fdiv_rn(dd[1], 10.0f);
            float dw = fminf(__fdiv_rn(dd[2], 5.0f), BBOX_CLIP);
            float dh = fminf(__fdiv_rn(dd[3], 5.0f), BBOX_CLIP);
            float pcx = __fadd_rn(__fmul_rn(dx, w), cx);
            float pcy = __fadd_rn(__fmul_rn(dy, h), cy);
            float pw  = __fmul_rn(expf(dw), w);
            float ph  = __fmul_rn(expf(dh), h);
            float bx1 = __fsub_rn(pcx, __fmul_rn(0.5f, pw));
            float by1 = __fsub_rn(pcy, __fmul_rn(0.5f, ph));
            float bx2 = __fsub_rn(__fadd_rn(pcx, __fmul_rn(0.5f, pw)), 1.0f);
            float by2 = __fsub_rn(__fadd_rn(pcy, __fmul_rn(0.5f, ph)), 1.0f);
            bx1 = fminf(fmaxf(bx1, 0.0f), IMG_MAX);
            by1 = fminf(fmaxf(by1, 0.0f), IMG_MAX);
            bx2 = fminf(fmaxf(bx2, 0.0f), IMG_MAX);
            by2 = fminf(fmaxf(by2, 0.0f), IMG_MAX);
            sbl[n] = make_float4(bx1, by1, bx2, by2);
        }
        if (tid < TKEEP / 64) remW[tid] = 0ull;   // first TKEEP fully processed
        __syncthreads();
        for (int k = 0; k < NN / TH1; ++k) {
            int j = k * TH1 + tid;
            bool sup = false;
            if (j >= TKEEP) {
                float4 c = sbl[j];
                for (int q = 0; q < keptNow; ++q) {
                    float4 a = sbl[keptPos[q]];
                    float aarea = __fmul_rn(__fadd_rn(__fsub_rn(a.z, a.x), 1.0f),
                                            __fadd_rn(__fsub_rn(a.w, a.y), 1.0f));
                    sup = sup || (iou_box(a, aarea, c) > NMS_TH);
                }
            }
            ull bm = __ballot(sup);
            if (lane == 0) remW[k * (TH1/64) + (tid >> 6)] &= ~bm;
        }
        __syncthreads();
        int kept = keptNow;
        while (kept < DETS) {
            ull mine = (lane < NN / 64) ? remW[lane] : 0ull;
            ull has = __ballot(mine != 0ull);
            if (has == 0ull) break;
            int fw = (int)__builtin_ctzll(has);
            unsigned lo = (unsigned)__shfl((int)(unsigned)mine, fw);
            unsigned hi = (unsigned)__shfl((int)(unsigned)(mine >> 32), fw);
            ull w64 = ((ull)hi << 32) | lo;
            int i = (fw << 6) + (int)__builtin_ctzll(w64);
            if (tid == 0) keptPos[kept] = i;
            ++kept;
            __syncthreads();
            float4 a = sbl[i];
            float aarea = __fmul_rn(__fadd_rn(__fsub_rn(a.z, a.x), 1.0f),
                                    __fadd_rn(__fsub_rn(a.w, a.y), 1.0f));
#pragma unroll
            for (int k = 0; k < NN / TH1; ++k) {
                int j = k * TH1 + tid;
                float iou = iou_box(a, aarea, sbl[j]);
                ull bm = __ballot(iou > NMS_TH);
                if (lane == 0) remW[k * (TH1/64) + (tid >> 6)] &= ~bm;
            }
            __syncthreads();
        }
        if (tid == 0) keptCnt = kept;
        __syncthreads();
    }

    // ---- Phase D: compact first <=100 kept + packed keys for the final top-k sort ----
    if (tid < DETS) {
        int kc = keptCnt;
        float sc = -1.0f, th = 0.0f;
        float4 bx = make_float4(0.f, 0.f, 0.f, 0.f);
        if (tid < kc) {
            int p = keptPos[tid];
            ull key = keys[p];
            sc = __uint_as_float((unsigned)(key >> 32));
            bx = sbl[p];
            int orig = NN - 1 - (int)(key & 0xFFFFFFFFull);
            th = D[(size_t)orig * NC * 5 + cls * 5 + 4];
        }
        int g = pair * DETS + tid;
        unsigned vb = __float_as_uint(sc);
        vb = (vb & 0x80000000u) ? ~vb : (vb | 0x80000000u);   // orderable
        // low bits: 2047 - image-local candidate index (monotone with ref flat index)
        cKey[g] = ((ull)vb << 32)
                | (unsigned)(NN - 1 - ((pair % NFG) * DETS + tid));
        cTheta[g] = th;
        ((float4*)cBox)[g] = bx;
    }
}

// -------- Kernel 2: per-image top-100 via hybrid bitonic over 1500 (pad 0) ----
__global__ __launch_bounds__(TH1)
void topk_kernel(const ull* __restrict__ cKey,
                 const float* __restrict__ cBox,
                 const float* __restrict__ cTheta,
                 float* __restrict__ out)
{
    const int b   = blockIdx.x;
    const int tid = threadIdx.x;
    const int M   = NFG * DETS;   // 1500

    __shared__ ull keys[NN];   // 16 KB

    const ull* src = cKey + (size_t)b * M;
    for (int t = tid; t < NN; t += TH1)
        keys[t] = (t < M) ? src[t] : 0ull;    // pad sorts last (real keys all > 0)
    __syncthreads();

    bitonic2048(keys, tid);

    if (tid < DETS) {
        ull key = keys[tid];
        unsigned vb = (unsigned)(key >> 32);
        float val = __uint_as_float((vb & 0x80000000u) ? (vb & 0x7FFFFFFFu) : ~vb);
        bool vld = (key != 0ull) && (val > 0.0f);
        float4 bx = make_float4(0.f, 0.f, 0.f, 0.f);
        float th = 0.f, lab = 0.f, scv = 0.f;
        if (vld) {
            int slot = NN - 1 - (int)(key & 0xFFFFFFFFull);  // clsfg*DETS + cidx
            size_t g = (size_t)b * M + slot;
            bx  = ((const float4*)cBox)[g];
            th  = cTheta[g];
            lab = (float)(slot / DETS + 1);
            scv = val;
        }
        int o = b * DETS + tid;
        // output: boxes[2][100][4] | scores[2][100] | theta[2][100] | labels[2][100] | valid[2][100]
        out[o * 4 + 0] = bx.x;
        out[o * 4 + 1] = bx.y;
        out[o * 4 + 2] = bx.z;
        out[o * 4 + 3] = bx.w;
        out[NB * DETS * 4 + o] = scv;
        out[NB * DETS * 5 + o] = th;
        out[NB * DETS * 6 + o] = lab;
        out[NB * DETS * 7 + o] = vld ? 1.0f : 0.0f;
    }
}

extern "C" void kernel_launch(void* const* d_in, const int* in_sizes, int n_in,
                              void* d_out, int out_size, void* d_ws, size_t ws_size,
                              hipStream_t stream) {
    const float* logits = (const float*)d_in[0];   // [2,2048,16]
    const float* deltas = (const float*)d_in[1];   // [2,2048,80]
    const float* props  = (const float*)d_in[2];   // [2,2048,4]
    float* out = (float*)d_out;                    // 1600 floats
    char* ws = (char*)d_ws;

    ull*   cKey     = (ull*)ws;                                   // NPAIR*DETS u64 (8B aligned)
    float* cBox     = (float*)(ws + sizeof(ull) * NPAIR * DETS);  // NPAIR*DETS*4
    float* cTheta   = cBox + (size_t)NPAIR * DETS * 4;            // NPAIR*DETS
    float* scoreAll = cTheta + (size_t)NPAIR * DETS;              // NPAIR*NN

    hipLaunchKernelGGL(score_kernel, dim3(NB * NN / 256), dim3(256), 0, stream,
                       logits, scoreAll);
    hipLaunchKernelGGL(nms_kernel, dim3(NPAIR), dim3(TH1), 0, stream,
                       scoreAll, deltas, props, cKey, cBox, cTheta);
    hipLaunchKernelGGL(topk_kernel, dim3(NB), dim3(TH1), 0, stream,
                       cKey, cBox, cTheta, out);
}